// Round 8
// baseline (598.783 us; speedup 1.0000x reference)
//
#include <hip/hip_runtime.h>
#include <cstdint>
#include <cstddef>

#define SEQ 5000
#define CIN 12
#define KL 9
#define ND 10
#define KPD 1000
#define NB 16
#define KPAD 128          // padded taps (108 -> 128)
#define NKP 1024          // padded kernels per dilation (1000 -> 1024)
#define BM 64             // t-points per block
#define NTILES 8          // NKP / 128 (tile = 128 kernels: 4 waves x 32)

typedef __attribute__((ext_vector_type(4))) float f32x4;
typedef __attribute__((ext_vector_type(8))) __bf16 bf16x8;
typedef __attribute__((ext_vector_type(8))) unsigned short u16x8;

__device__ __forceinline__ unsigned fkey(float f) {
    unsigned u = __float_as_uint(f);
    return (u & 0x80000000u) ? ~u : (u | 0x80000000u);
}
__device__ __forceinline__ float unfkey(unsigned k) {
    unsigned u = (k & 0x80000000u) ? (k ^ 0x80000000u) : ~k;
    return __uint_as_float(u);
}
__device__ __forceinline__ unsigned short f2bf(float f) {
    unsigned u = __float_as_uint(f);
    u += 0x7fffu + ((u >> 16) & 1u);
    return (unsigned short)(u >> 16);
}

// ---- weight prep: [10][1000][108] f32 -> [10][1024][128] bf16, zero-padded ----
__global__ __launch_bounds__(256) void wprep(const float* __restrict__ w,
                                             unsigned short* __restrict__ wbf) {
    const int i = blockIdx.x * 256 + threadIdx.x;   // over ND*NKP*KPAD
    if (i >= ND * NKP * KPAD) return;
    const int kk   = i & (KPAD - 1);
    const int krow = (i >> 7) & (NKP - 1);
    const int di   = i >> 17;
    float v = 0.f;
    if (krow < KPD && kk < CIN * KL)
        v = w[((size_t)di * KPD + krow) * (CIN * KL) + kk];
    wbf[i] = f2bf(v);
}

template <bool TAIL>
__device__ __forceinline__ void mr_body(
    const float* __restrict__ xb, const unsigned short* __restrict__ wd,
    const float* __restrict__ bb, unsigned* __restrict__ gkey,
    unsigned* __restrict__ gcnt, int d, int t0,
    unsigned short* lA, size_t slotbase)
{
    const int tid  = threadIdx.x;
    const int lane = tid & 63;
    const int wv   = tid >> 6;

    // ---- gather patch A[64][128] into swizzled LDS (lane = t -> coalesced x reads) ----
    {
        const int row  = tid & 63;
        const int cw   = tid >> 6;           // col group: 32 taps each
        const int base = t0 + row - 4 * d;   // SAME padding: pad_lo = 4d
        int cc = cw * 32;
        int c = cc / 9, j = cc - c * 9;
#pragma unroll
        for (int m = 0; m < 4; ++m) {
            u16x8 pk;
#pragma unroll
            for (int e = 0; e < 8; ++e) {
                const int idx = base + j * d;
                float v = 0.f;
                if ((cc < CIN * KL) && idx >= 0 && idx < SEQ) v = xb[c * SEQ + idx];
                pk[e] = f2bf(v);
                ++cc;
                if (++j == KL) { j = 0; ++c; }
            }
            const int cb   = cw * 64 + m * 16;
            const int addr = row * 256 + (cb ^ ((row & 7) << 4));
            *(u16x8*)((char*)lA + addr) = pk;
        }
    }
    __syncthreads();

    const int fr = lane & 15;   // frag row (t within 16) / frag col (kernel within 16)
    const int ks = lane >> 4;   // k-slice group

    // precomputed swizzled LDS byte addrs for the 16 A-fragments (SGPR-friendly)
    int aaddr[4][4];
#pragma unroll
    for (int m = 0; m < 4; ++m) {
        const int row = m * 16 + fr;
#pragma unroll
        for (int kk = 0; kk < 4; ++kk) {
            const int cb = kk * 64 + ks * 16;
            aaddr[m][kk] = row * 256 + (cb ^ ((row & 7) << 4));
        }
    }

    // per-lane W base for this wave's two 16-kernel columns within each 128-tile
    const unsigned short* wb0 = wd + (size_t)(wv * 32 + fr) * KPAD + ks * 8;

    for (int kt = 0; kt < NTILES; ++kt) {
        const unsigned short* w0 = wb0 + (size_t)kt * 128 * KPAD;
        const unsigned short* w1 = w0 + 16 * KPAD;
        bf16x8 b0[4], b1[4];
#pragma unroll
        for (int kk = 0; kk < 4; ++kk) {
            b0[kk] = *(const bf16x8*)(w0 + kk * 32);
            b1[kk] = *(const bf16x8*)(w1 + kk * 32);
        }

        f32x4 acc0[4], acc1[4];
#pragma unroll
        for (int m = 0; m < 4; ++m) {
            acc0[m] = (f32x4){0.f, 0.f, 0.f, 0.f};
            acc1[m] = (f32x4){0.f, 0.f, 0.f, 0.f};
        }

        // each A-frag read once (LDS), used by TWO MFMAs -> A-traffic halved
#pragma unroll
        for (int m = 0; m < 4; ++m) {
#pragma unroll
            for (int kk = 0; kk < 4; ++kk) {
                const bf16x8 a = *(const bf16x8*)((const char*)lA + aaddr[m][kk]);
                acc0[m] = __builtin_amdgcn_mfma_f32_16x16x32_bf16(a, b0[kk], acc0[m], 0, 0, 0);
                acc1[m] = __builtin_amdgcn_mfma_f32_16x16x32_bf16(a, b1[kk], acc1[m], 0, 0, 0);
            }
        }

        // ---- epilogue for the two 16-kernel columns ----
#pragma unroll
        for (int n = 0; n < 2; ++n) {
            const f32x4* acc = n ? acc1 : acc0;
            const int kcol = kt * 128 + wv * 32 + n * 16 + fr;
            const float bv = (kcol < KPD) ? bb[kcol] : 3.0e38f;

            unsigned pcnt = 0;
            float pm[4];
#pragma unroll
            for (int m = 0; m < 4; ++m) {
                float x0 = acc[m][0], x1 = acc[m][1], x2 = acc[m][2], x3 = acc[m][3];
                if (TAIL) {
                    const int tbase = t0 + m * 16 + ks * 4;
                    x0 = (tbase + 0 < SEQ) ? x0 : -3.0e38f;
                    x1 = (tbase + 1 < SEQ) ? x1 : -3.0e38f;
                    x2 = (tbase + 2 < SEQ) ? x2 : -3.0e38f;
                    x3 = (tbase + 3 < SEQ) ? x3 : -3.0e38f;
                }
                pcnt += (x0 > bv) ? 1u : 0u;
                pcnt += (x1 > bv) ? 1u : 0u;
                pcnt += (x2 > bv) ? 1u : 0u;
                pcnt += (x3 > bv) ? 1u : 0u;
                pm[m] = fmaxf(fmaxf(x0, x1), fmaxf(x2, x3));
            }
            float pmax = fmaxf(fmaxf(pm[0], pm[1]), fmaxf(pm[2], pm[3]));

            pmax = fmaxf(pmax, __shfl_xor(pmax, 16, 64));
            pcnt += (unsigned)__shfl_xor((int)pcnt, 16, 64);
            pmax = fmaxf(pmax, __shfl_xor(pmax, 32, 64));
            pcnt += (unsigned)__shfl_xor((int)pcnt, 32, 64);
            if (ks == 0 && kcol < KPD) {
                atomicMax(&gkey[slotbase + kcol], fkey(pmax));
                atomicAdd(&gcnt[slotbase + kcol], pcnt);
            }
        }
    }
}

// grid: (79 t-chunks, ND, NB), block 256
__global__ __launch_bounds__(256) void mr_main(
    const float* __restrict__ x, const unsigned short* __restrict__ wbf,
    const float* __restrict__ bias, unsigned* __restrict__ gkey,
    unsigned* __restrict__ gcnt)
{
    const int tb = blockIdx.x;
    const int di = blockIdx.y;
    const int b  = blockIdx.z;
    const int d  = 1 << di;
    const int t0 = tb * BM;

    __shared__ __align__(16) unsigned short lA[BM * KPAD];

    const float* xb = x + (size_t)b * CIN * SEQ;
    const unsigned short* wd = wbf + (size_t)di * NKP * KPAD;
    const float* bb = bias + (size_t)di * KPD;
    const size_t slotbase = ((size_t)b * ND + di) * KPD;

    if (t0 + BM <= SEQ)
        mr_body<false>(xb, wd, bb, gkey, gcnt, d, t0, lA, slotbase);
    else
        mr_body<true>(xb, wd, bb, gkey, gcnt, d, t0, lA, slotbase);
}

__global__ __launch_bounds__(256) void mr_fin(
    const unsigned* __restrict__ gkey, const unsigned* __restrict__ gcnt,
    float* __restrict__ out)
{
    const int i = blockIdx.x * 256 + threadIdx.x;   // over NB*ND*KPD
    if (i >= NB * ND * KPD) return;
    const int k  = i % KPD;
    const int di = (i / KPD) % ND;
    const int b  = i / (KPD * ND);
    const float maxv = unfkey(gkey[i]);
    const float ppv  = (float)gcnt[i] * (1.0f / (float)SEQ);
    float* ob = out + (size_t)b * (2 * ND * KPD);
    ob[di * 2 * KPD + k]       = maxv;
    ob[di * 2 * KPD + KPD + k] = ppv;
}

extern "C" void kernel_launch(void* const* d_in, const int* in_sizes, int n_in,
                              void* d_out, int out_size, void* d_ws, size_t ws_size,
                              hipStream_t stream) {
    const float* x    = (const float*)d_in[0];
    const float* w    = (const float*)d_in[1];
    const float* bias = (const float*)d_in[2];
    float* out = (float*)d_out;

    unsigned* gkey = (unsigned*)d_ws;
    unsigned* gcnt = gkey + (size_t)NB * ND * KPD;
    unsigned short* wbf = (unsigned short*)(gcnt + (size_t)NB * ND * KPD);

    hipMemsetAsync(d_ws, 0, (size_t)NB * ND * KPD * 2 * sizeof(unsigned), stream);

    const int wtot = ND * NKP * KPAD;
    wprep<<<(wtot + 255) / 256, 256, 0, stream>>>(w, wbf);

    dim3 grid((SEQ + BM - 1) / BM, ND, NB);
    mr_main<<<grid, 256, 0, stream>>>(x, wbf, bias, gkey, gcnt);

    const int tot = NB * ND * KPD;
    mr_fin<<<(tot + 255) / 256, 256, 0, stream>>>(gkey, gcnt, out);
}

// Round 9
// 544.462 us; speedup vs baseline: 1.0998x; 1.0998x over previous
//
#include <hip/hip_runtime.h>
#include <cstdint>
#include <cstddef>

#define SEQ 5000
#define CIN 12
#define KL 9
#define ND 10
#define KPD 1000
#define NB 16
#define KPAD 128          // padded taps (108 -> 128)
#define NKP 1024          // padded kernels per dilation (1000 -> 1024)
#define BM 64             // t-points per block
#define NTILES 8          // NKP / 128 (tile = 128 kernels: 4 waves x 2x16)

typedef __attribute__((ext_vector_type(4))) float f32x4;
typedef __attribute__((ext_vector_type(8))) __bf16 bf16x8;
typedef __attribute__((ext_vector_type(8))) unsigned short u16x8;

__device__ __forceinline__ unsigned fkey(float f) {
    unsigned u = __float_as_uint(f);
    return (u & 0x80000000u) ? ~u : (u | 0x80000000u);
}
__device__ __forceinline__ float unfkey(unsigned k) {
    unsigned u = (k & 0x80000000u) ? (k ^ 0x80000000u) : ~k;
    return __uint_as_float(u);
}
__device__ __forceinline__ unsigned short f2bf(float f) {
    unsigned u = __float_as_uint(f);
    u += 0x7fffu + ((u >> 16) & 1u);
    return (unsigned short)(u >> 16);
}

// ---- weight prep: [10][1000][108] f32 -> [10][1024][128] bf16, zero-padded ----
__global__ __launch_bounds__(256) void wprep(const float* __restrict__ w,
                                             unsigned short* __restrict__ wbf) {
    const int i = blockIdx.x * 256 + threadIdx.x;   // over ND*NKP*KPAD
    if (i >= ND * NKP * KPAD) return;
    const int kk   = i & (KPAD - 1);
    const int krow = (i >> 7) & (NKP - 1);
    const int di   = i >> 17;
    float v = 0.f;
    if (krow < KPD && kk < CIN * KL)
        v = w[((size_t)di * KPD + krow) * (CIN * KL) + kk];
    wbf[i] = f2bf(v);
}

template <bool TAIL>
__device__ __forceinline__ void mr_body(
    const float* __restrict__ xb, const unsigned short* __restrict__ wd,
    const float* __restrict__ bb, unsigned* __restrict__ gkey,
    unsigned* __restrict__ gcnt, int d, int t0,
    unsigned short* lA, size_t slotbase)
{
    const int tid  = threadIdx.x;
    const int lane = tid & 63;
    const int wv   = tid >> 6;

    // ---- gather patch A[64][128] into swizzled LDS (lane = t -> coalesced x reads) ----
    {
        const int row  = tid & 63;
        const int cw   = tid >> 6;           // col group: 32 taps each
        const int base = t0 + row - 4 * d;   // SAME padding: pad_lo = 4d
        int cc = cw * 32;
        int c = cc / 9, j = cc - c * 9;
#pragma unroll
        for (int m = 0; m < 4; ++m) {
            u16x8 pk;
#pragma unroll
            for (int e = 0; e < 8; ++e) {
                const int idx = base + j * d;
                float v = 0.f;
                if ((cc < CIN * KL) && idx >= 0 && idx < SEQ) v = xb[c * SEQ + idx];
                pk[e] = f2bf(v);
                ++cc;
                if (++j == KL) { j = 0; ++c; }
            }
            const int cb   = cw * 64 + m * 16;
            const int addr = row * 256 + (cb ^ ((row & 7) << 4));
            *(u16x8*)((char*)lA + addr) = pk;
        }
    }
    __syncthreads();

    const int fr = lane & 15;   // frag row (t within 16) / frag col (kernel within 16)
    const int ks = lane >> 4;   // k-slice group

    // Swizzled A addrs: addr(m,kk) = row*256 + ((kk<<6) ^ (ks<<4) ^ ((row&7)<<4)).
    // bit7 of the low part is always clear -> kk=2,3 are +128 offsets (folded
    // into ds_read imm), so only 2 address regs per m-strip.
    int a0[4], a1[4];
#pragma unroll
    for (int m = 0; m < 4; ++m) {
        const int row  = m * 16 + fr;
        const int base = row * 256 + ((ks * 16) ^ ((row & 7) << 4));
        a0[m] = base;
        a1[m] = base ^ 64;
    }

    // per-lane W base for this wave's two 16-kernel columns within each 128-tile
    const unsigned short* wb0 = wd + (size_t)(wv * 32 + fr) * KPAD + ks * 8;

    // prologue: load tile-0 B fragments
    bf16x8 b0[4], b1[4];
#pragma unroll
    for (int kk = 0; kk < 4; ++kk) {
        b0[kk] = *(const bf16x8*)(wb0 + kk * 32);
        b1[kk] = *(const bf16x8*)(wb0 + 16 * KPAD + kk * 32);
    }

    for (int kt = 0; kt < NTILES; ++kt) {
        f32x4 acc0[4], acc1[4];
#pragma unroll
        for (int m = 0; m < 4; ++m) {
            acc0[m] = (f32x4){0.f, 0.f, 0.f, 0.f};
            acc1[m] = (f32x4){0.f, 0.f, 0.f, 0.f};
        }

        // each A-frag read once (LDS), feeds TWO MFMAs -> 0.5 ds_read/MFMA
#pragma unroll
        for (int m = 0; m < 4; ++m) {
            const char* pa0 = (const char*)lA + a0[m];
            const char* pa1 = (const char*)lA + a1[m];
#pragma unroll
            for (int kk = 0; kk < 4; ++kk) {
                const char* p = (kk & 1) ? pa1 : pa0;
                const bf16x8 a = *(const bf16x8*)(p + (kk >> 1) * 128);
                acc0[m] = __builtin_amdgcn_mfma_f32_16x16x32_bf16(a, b0[kk], acc0[m], 0, 0, 0);
                acc1[m] = __builtin_amdgcn_mfma_f32_16x16x32_bf16(a, b1[kk], acc1[m], 0, 0, 0);
            }
        }

        // issue NEXT tile's B loads now: latency hides under epilogue + next
        // tile's ds_reads. sched_barrier stops the compiler sinking them
        // (r8 regression: loads at use point -> ~250cyc L2 latency per tile).
        const int ktn = (kt + 1) & (NTILES - 1);
        const unsigned short* wn = wb0 + (size_t)ktn * 128 * KPAD;
        bf16x8 bn0[4], bn1[4];
#pragma unroll
        for (int kk = 0; kk < 4; ++kk) {
            bn0[kk] = *(const bf16x8*)(wn + kk * 32);
            bn1[kk] = *(const bf16x8*)(wn + 16 * KPAD + kk * 32);
        }
        __builtin_amdgcn_sched_barrier(0);

        // ---- epilogue for the two 16-kernel columns ----
#pragma unroll
        for (int n = 0; n < 2; ++n) {
            const f32x4* acc = n ? acc1 : acc0;
            const int kcol = kt * 128 + wv * 32 + n * 16 + fr;
            const float bv = (kcol < KPD) ? bb[kcol] : 3.0e38f;

            unsigned pcnt = 0;
            float pm[4];
#pragma unroll
            for (int m = 0; m < 4; ++m) {
                float x0 = acc[m][0], x1 = acc[m][1], x2 = acc[m][2], x3 = acc[m][3];
                if (TAIL) {
                    const int tbase = t0 + m * 16 + ks * 4;
                    x0 = (tbase + 0 < SEQ) ? x0 : -3.0e38f;
                    x1 = (tbase + 1 < SEQ) ? x1 : -3.0e38f;
                    x2 = (tbase + 2 < SEQ) ? x2 : -3.0e38f;
                    x3 = (tbase + 3 < SEQ) ? x3 : -3.0e38f;
                }
                pcnt += (x0 > bv) ? 1u : 0u;
                pcnt += (x1 > bv) ? 1u : 0u;
                pcnt += (x2 > bv) ? 1u : 0u;
                pcnt += (x3 > bv) ? 1u : 0u;
                pm[m] = fmaxf(fmaxf(x0, x1), fmaxf(x2, x3));
            }
            float pmax = fmaxf(fmaxf(pm[0], pm[1]), fmaxf(pm[2], pm[3]));

            pmax = fmaxf(pmax, __shfl_xor(pmax, 16, 64));
            pcnt += (unsigned)__shfl_xor((int)pcnt, 16, 64);
            pmax = fmaxf(pmax, __shfl_xor(pmax, 32, 64));
            pcnt += (unsigned)__shfl_xor((int)pcnt, 32, 64);
            if (ks == 0 && kcol < KPD) {
                atomicMax(&gkey[slotbase + kcol], fkey(pmax));
                atomicAdd(&gcnt[slotbase + kcol], pcnt);
            }
        }

#pragma unroll
        for (int kk = 0; kk < 4; ++kk) { b0[kk] = bn0[kk]; b1[kk] = bn1[kk]; }
    }
}

// grid: (79 t-chunks, ND, NB), block 256
__global__ __launch_bounds__(256) void mr_main(
    const float* __restrict__ x, const unsigned short* __restrict__ wbf,
    const float* __restrict__ bias, unsigned* __restrict__ gkey,
    unsigned* __restrict__ gcnt)
{
    const int tb = blockIdx.x;
    const int di = blockIdx.y;
    const int b  = blockIdx.z;
    const int d  = 1 << di;
    const int t0 = tb * BM;

    __shared__ __align__(16) unsigned short lA[BM * KPAD];

    const float* xb = x + (size_t)b * CIN * SEQ;
    const unsigned short* wd = wbf + (size_t)di * NKP * KPAD;
    const float* bb = bias + (size_t)di * KPD;
    const size_t slotbase = ((size_t)b * ND + di) * KPD;

    if (t0 + BM <= SEQ)
        mr_body<false>(xb, wd, bb, gkey, gcnt, d, t0, lA, slotbase);
    else
        mr_body<true>(xb, wd, bb, gkey, gcnt, d, t0, lA, slotbase);
}

__global__ __launch_bounds__(256) void mr_fin(
    const unsigned* __restrict__ gkey, const unsigned* __restrict__ gcnt,
    float* __restrict__ out)
{
    const int i = blockIdx.x * 256 + threadIdx.x;   // over NB*ND*KPD
    if (i >= NB * ND * KPD) return;
    const int k  = i % KPD;
    const int di = (i / KPD) % ND;
    const int b  = i / (KPD * ND);
    const float maxv = unfkey(gkey[i]);
    const float ppv  = (float)gcnt[i] * (1.0f / (float)SEQ);
    float* ob = out + (size_t)b * (2 * ND * KPD);
    ob[di * 2 * KPD + k]       = maxv;
    ob[di * 2 * KPD + KPD + k] = ppv;
}

extern "C" void kernel_launch(void* const* d_in, const int* in_sizes, int n_in,
                              void* d_out, int out_size, void* d_ws, size_t ws_size,
                              hipStream_t stream) {
    const float* x    = (const float*)d_in[0];
    const float* w    = (const float*)d_in[1];
    const float* bias = (const float*)d_in[2];
    float* out = (float*)d_out;

    unsigned* gkey = (unsigned*)d_ws;
    unsigned* gcnt = gkey + (size_t)NB * ND * KPD;
    unsigned short* wbf = (unsigned short*)(gcnt + (size_t)NB * ND * KPD);

    hipMemsetAsync(d_ws, 0, (size_t)NB * ND * KPD * 2 * sizeof(unsigned), stream);

    const int wtot = ND * NKP * KPAD;
    wprep<<<(wtot + 255) / 256, 256, 0, stream>>>(w, wbf);

    dim3 grid((SEQ + BM - 1) / BM, ND, NB);
    mr_main<<<grid, 256, 0, stream>>>(x, wbf, bias, gkey, gcnt);

    const int tot = NB * ND * KPD;
    mr_fin<<<(tot + 255) / 256, 256, 0, stream>>>(gkey, gcnt, out);
}

// Round 10
// 336.025 us; speedup vs baseline: 1.7820x; 1.6203x over previous
//
#include <hip/hip_runtime.h>
#include <cstdint>
#include <cstddef>

#define SEQ 5000
#define CIN 12
#define KL 9
#define ND 10
#define KPD 1000
#define NB 16
#define KPAD 128              // padded taps (108 -> 128)
#define NKP 1024              // padded kernels per dilation
#define BM 64                 // t-rows per strip
#define SPB 79                // strips per batch = ceil(5000/64)
#define STRIP_US (BM * KPAD)  // 8192 ushorts = 16KB per strip
#define QS 20                 // strips per quarter (last quarter: 19)

typedef __attribute__((ext_vector_type(4))) float f32x4;
typedef __attribute__((ext_vector_type(8))) __bf16 bf16x8;
typedef __attribute__((ext_vector_type(8))) unsigned short u16x8;

__device__ __forceinline__ unsigned fkey(float f) {
    unsigned u = __float_as_uint(f);
    return (u & 0x80000000u) ? ~u : (u | 0x80000000u);
}
__device__ __forceinline__ float unfkey(unsigned k) {
    unsigned u = (k & 0x80000000u) ? (k ^ 0x80000000u) : ~k;
    return __uint_as_float(u);
}
__device__ __forceinline__ unsigned short f2bf(float f) {
    unsigned u = __float_as_uint(f);
    u += 0x7fffu + ((u >> 16) & 1u);
    return (unsigned short)(u >> 16);
}

// ---- weight prep: [10][1000][108] f32 -> [10][1024][128] bf16, zero-padded ----
__global__ __launch_bounds__(256) void wprep(const float* __restrict__ w,
                                             unsigned short* __restrict__ wbf) {
    const int i = blockIdx.x * 256 + threadIdx.x;
    if (i >= ND * NKP * KPAD) return;
    const int kk   = i & (KPAD - 1);
    const int krow = (i >> 7) & (NKP - 1);
    const int di   = i >> 17;
    float v = 0.f;
    if (krow < KPD && kk < CIN * KL)
        v = w[((size_t)di * KPD + krow) * (CIN * KL) + kk];
    wbf[i] = f2bf(v);
}

// ---- im2col: x -> Aim[dl][b][strip][row 64][128 taps] bf16, PRE-SWIZZLED ----
// byte layout within strip: row*256 + ((cw*16) ^ ((row&7)<<4))  (16B units)
// so gload_lds stages LINEARLY and ds_read applies the same swizzle (rule 21).
__global__ __launch_bounds__(256) void im2col(const float* __restrict__ x,
                                              unsigned short* __restrict__ Aim,
                                              int g0) {
    const int s  = blockIdx.x;
    const int b  = blockIdx.y;
    const int dl = blockIdx.z;
    const int d  = 1 << (g0 + dl);
    const int tid = threadIdx.x;
    unsigned short* outp = Aim + ((size_t)(dl * NB + b) * SPB + s) * STRIP_US;
    const float* xb = x + (size_t)b * CIN * SEQ;
    const int t0 = s * BM;
#pragma unroll
    for (int it = 0; it < 4; ++it) {
        const int uid = it * 256 + tid;
        const int row = uid >> 4;
        const int cw  = uid & 15;
        const int t   = t0 + row;
        int cc = cw * 8;
        int c = cc / 9, j = cc - c * 9;
        const int base = t - 4 * d;      // SAME padding: pad_lo = 4d
        u16x8 pk;
#pragma unroll
        for (int e = 0; e < 8; ++e) {
            const int idx = base + j * d;
            float v = 0.f;
            if (t < SEQ && cc < CIN * KL && idx >= 0 && idx < SEQ)
                v = xb[c * SEQ + idx];
            pk[e] = f2bf(v);
            ++cc; if (++j == KL) { j = 0; ++c; }
        }
        *(u16x8*)(outp + row * KPAD + ((cw * 8) ^ ((row & 7) << 3))) = pk;
    }
}

// ---- main GEMM-reduce: block = (dl, ksub of 128 kernels, batch, quarter) ----
__global__ __launch_bounds__(256, 4) void mr_gemm(
    const unsigned short* __restrict__ Aim,
    const unsigned short* __restrict__ wbf,
    const float* __restrict__ bias,
    unsigned* __restrict__ gkey, unsigned* __restrict__ gcnt, int g0)
{
    __shared__ __align__(16) unsigned short lA[2][STRIP_US];  // 32KB dbuf

    // XCD-bijective remap: the 8 ksub-siblings of one (dl,b,q) share phys%8
    // -> same XCD L2 caches their common A-slice once.
    const int phys = blockIdx.x;
    const int gg   = ((phys >> 6) << 3) | (phys & 7);
    const int ksub = (phys >> 3) & 7;
    const int q  = gg & 3;
    const int b  = (gg >> 2) & 15;
    const int dl = gg >> 6;
    const int di = g0 + dl;

    const int tid  = threadIdx.x;
    const int lane = tid & 63;
    const int wv   = tid >> 6;
    const int fr   = lane & 15;
    const int ks   = lane >> 4;

    const int sBeg = q * QS;
    const int sEnd = (q == 3) ? SPB : (sBeg + QS);

    const unsigned short* Ab = Aim + (size_t)(dl * NB + b) * SPB * STRIP_US;
    const unsigned short* wd = wbf + (size_t)di * NKP * KPAD;
    const int kc0 = ksub * 128 + wv * 32 + fr;
    const int kc1 = kc0 + 16;
    const unsigned short* wp = wd + (size_t)kc0 * KPAD + ks * 8;

    // B fragments: loaded ONCE per block (loop-invariant, 32 VGPRs)
    bf16x8 b0[4], b1[4];
#pragma unroll
    for (int kk = 0; kk < 4; ++kk) {
        b0[kk] = *(const bf16x8*)(wp + kk * 32);
        b1[kk] = *(const bf16x8*)(wp + 16 * KPAD + kk * 32);
    }
    const float* bb = bias + (size_t)di * KPD;
    const float bv0 = (kc0 < KPD) ? bb[kc0] : 3.0e38f;
    const float bv1 = (kc1 < KPD) ? bb[kc1] : 3.0e38f;

    float rmax0 = -3.0e38f, rmax1 = -3.0e38f;
    unsigned rcnt0 = 0, rcnt1 = 0;

    // swizzled A-frag base byte addrs (bit7 clear -> +128 folds as imm)
    int abase[4];
#pragma unroll
    for (int m = 0; m < 4; ++m) {
        const int row = m * 16 + fr;
        abase[m] = row * 256 + ((ks * 16) ^ ((row & 7) << 4));
    }

    // prologue: stage strip sBeg into buf0 (linear dest, lane*16 implicit)
    {
        const char* src = (const char*)(Ab + (size_t)sBeg * STRIP_US) + wv * 4096 + lane * 16;
        char* dst = (char*)&lA[0][0] + wv * 4096;
#pragma unroll
        for (int i = 0; i < 4; ++i)
            __builtin_amdgcn_global_load_lds(
                (const __attribute__((address_space(1))) unsigned int*)(src + i * 1024),
                (__attribute__((address_space(3))) unsigned int*)(dst + i * 1024),
                16, 0, 0);
    }
    __syncthreads();

    for (int s = sBeg; s < sEnd; ++s) {
        const int cur = (s - sBeg) & 1;
        if (s + 1 < sEnd) {   // stage next strip into other buffer
            const char* src = (const char*)(Ab + (size_t)(s + 1) * STRIP_US) + wv * 4096 + lane * 16;
            char* dst = (char*)&lA[cur ^ 1][0] + wv * 4096;
#pragma unroll
            for (int i = 0; i < 4; ++i)
                __builtin_amdgcn_global_load_lds(
                    (const __attribute__((address_space(1))) unsigned int*)(src + i * 1024),
                    (__attribute__((address_space(3))) unsigned int*)(dst + i * 1024),
                    16, 0, 0);
        }

        const char* bufc = (const char*)&lA[cur][0];
        f32x4 acc0[4], acc1[4];
#pragma unroll
        for (int m = 0; m < 4; ++m) {
            acc0[m] = (f32x4){0.f, 0.f, 0.f, 0.f};
            acc1[m] = (f32x4){0.f, 0.f, 0.f, 0.f};
        }
        // each A-frag read once, feeds TWO MFMAs (0.5 ds_read/MFMA)
#pragma unroll
        for (int m = 0; m < 4; ++m) {
            const char* pa0 = bufc + abase[m];
            const char* pa1 = bufc + (abase[m] ^ 64);
#pragma unroll
            for (int kk = 0; kk < 4; ++kk) {
                const char* p = (kk & 1) ? pa1 : pa0;
                const bf16x8 a = *(const bf16x8*)(p + (kk >> 1) * 128);
                acc0[m] = __builtin_amdgcn_mfma_f32_16x16x32_bf16(a, b0[kk], acc0[m], 0, 0, 0);
                acc1[m] = __builtin_amdgcn_mfma_f32_16x16x32_bf16(a, b1[kk], acc1[m], 0, 0, 0);
            }
        }

        // per-lane running stats: NO shuffles / atomics per strip
        if (s != SPB - 1) {
            float m0 = -3.0e38f, m1 = -3.0e38f;
            unsigned c0 = 0, c1 = 0;
#pragma unroll
            for (int m = 0; m < 4; ++m) {
#pragma unroll
                for (int r = 0; r < 4; ++r) {
                    const float x0 = acc0[m][r], x1 = acc1[m][r];
                    m0 = fmaxf(m0, x0); c0 += (x0 > bv0) ? 1u : 0u;
                    m1 = fmaxf(m1, x1); c1 += (x1 > bv1) ? 1u : 0u;
                }
            }
            rmax0 = fmaxf(rmax0, m0); rcnt0 += c0;
            rmax1 = fmaxf(rmax1, m1); rcnt1 += c1;
        } else {
            // tail strip 78: rows 4992..5055, valid t<5000 -> rows 0..7 only
            if (ks < 2) {
#pragma unroll
                for (int r = 0; r < 4; ++r) {
                    const float x0 = acc0[0][r], x1 = acc1[0][r];
                    rmax0 = fmaxf(rmax0, x0); rcnt0 += (x0 > bv0) ? 1u : 0u;
                    rmax1 = fmaxf(rmax1, x1); rcnt1 += (x1 > bv1) ? 1u : 0u;
                }
            }
        }
        __syncthreads();   // reads of cur done + stage of cur^1 landed
    }

    // ONE cross-lane reduce + atomic per block (amortized over ~20 strips)
    rmax0 = fmaxf(rmax0, __shfl_xor(rmax0, 16, 64));
    rcnt0 += (unsigned)__shfl_xor((int)rcnt0, 16, 64);
    rmax0 = fmaxf(rmax0, __shfl_xor(rmax0, 32, 64));
    rcnt0 += (unsigned)__shfl_xor((int)rcnt0, 32, 64);
    rmax1 = fmaxf(rmax1, __shfl_xor(rmax1, 16, 64));
    rcnt1 += (unsigned)__shfl_xor((int)rcnt1, 16, 64);
    rmax1 = fmaxf(rmax1, __shfl_xor(rmax1, 32, 64));
    rcnt1 += (unsigned)__shfl_xor((int)rcnt1, 32, 64);

    if (lane < 16) {
        const size_t slotbase = ((size_t)b * ND + di) * KPD;
        if (kc0 < KPD) {
            atomicMax(&gkey[slotbase + kc0], fkey(rmax0));
            atomicAdd(&gcnt[slotbase + kc0], rcnt0);
        }
        if (kc1 < KPD) {
            atomicMax(&gkey[slotbase + kc1], fkey(rmax1));
            atomicAdd(&gcnt[slotbase + kc1], rcnt1);
        }
    }
}

__global__ __launch_bounds__(256) void mr_fin(
    const unsigned* __restrict__ gkey, const unsigned* __restrict__ gcnt,
    float* __restrict__ out)
{
    const int i = blockIdx.x * 256 + threadIdx.x;   // over NB*ND*KPD
    if (i >= NB * ND * KPD) return;
    const int k  = i % KPD;
    const int di = (i / KPD) % ND;
    const int b  = i / (KPD * ND);
    const float maxv = unfkey(gkey[i]);
    const float ppv  = (float)gcnt[i] * (1.0f / (float)SEQ);
    float* ob = out + (size_t)b * (2 * ND * KPD);
    ob[di * 2 * KPD + k]       = maxv;
    ob[di * 2 * KPD + KPD + k] = ppv;
}

extern "C" void kernel_launch(void* const* d_in, const int* in_sizes, int n_in,
                              void* d_out, int out_size, void* d_ws, size_t ws_size,
                              hipStream_t stream) {
    const float* x    = (const float*)d_in[0];
    const float* w    = (const float*)d_in[1];
    const float* bias = (const float*)d_in[2];
    float* out = (float*)d_out;

    const size_t statsB = (size_t)NB * ND * KPD * 4;        // 640,000 B
    const size_t wbfB   = (size_t)ND * NKP * KPAD * 2;      // 2,621,440 B
    unsigned* gkey = (unsigned*)d_ws;
    unsigned* gcnt = (unsigned*)((char*)d_ws + statsB);
    unsigned short* wbf = (unsigned short*)((char*)d_ws + 2 * statsB);
    unsigned short* Aim = (unsigned short*)((char*)d_ws + 2 * statsB + wbfB);

    // group dilations to fit Aim in the available workspace
    const size_t perDil = (size_t)NB * SPB * STRIP_US * 2;  // 20,709,376 B
    const size_t head = 2 * statsB + wbfB;
    size_t avail = (ws_size > head) ? (ws_size - head) : 0;
    int NG = (int)(avail / perDil);
    if (NG > ND) NG = ND;
    if (NG < 1) NG = 1;

    hipMemsetAsync(d_ws, 0, 2 * statsB, stream);

    const int wtot = ND * NKP * KPAD;
    wprep<<<(wtot + 255) / 256, 256, 0, stream>>>(w, wbf);

    for (int g0 = 0; g0 < ND; g0 += NG) {
        const int ng = (ND - g0 < NG) ? (ND - g0) : NG;
        im2col<<<dim3(SPB, NB, ng), 256, 0, stream>>>(x, Aim, g0);
        mr_gemm<<<ng * 512, 256, 0, stream>>>(Aim, wbf, bias, gkey, gcnt, g0);
    }

    const int tot = NB * ND * KPD;
    mr_fin<<<(tot + 255) / 256, 256, 0, stream>>>(gkey, gcnt, out);
}

// Round 11
// 284.631 us; speedup vs baseline: 2.1037x; 1.1806x over previous
//
#include <hip/hip_runtime.h>
#include <cstdint>
#include <cstddef>

#define SEQ 5000
#define CIN 12
#define KL 9
#define ND 10
#define KPD 1000
#define NB 16
#define KPAD 128              // padded taps (108 -> 128)
#define NKP 1024              // padded kernels per dilation
#define BM 64                 // t-rows per strip
#define SPB 79                // strips per batch = ceil(5000/64)
#define STRIP_US (BM * KPAD)  // 8192 ushorts = 16KB per strip
#define QS 20                 // strips per quarter (last quarter: 19)

typedef __attribute__((ext_vector_type(4))) float f32x4;
typedef __attribute__((ext_vector_type(8))) __bf16 bf16x8;
typedef __attribute__((ext_vector_type(8))) unsigned short u16x8;

__device__ __forceinline__ unsigned fkey(float f) {
    unsigned u = __float_as_uint(f);
    return (u & 0x80000000u) ? ~u : (u | 0x80000000u);
}
__device__ __forceinline__ float unfkey(unsigned k) {
    unsigned u = (k & 0x80000000u) ? (k ^ 0x80000000u) : ~k;
    return __uint_as_float(u);
}
__device__ __forceinline__ unsigned short f2bf(float f) {
    unsigned u = __float_as_uint(f);
    u += 0x7fffu + ((u >> 16) & 1u);
    return (unsigned short)(u >> 16);
}

// ---- weight prep: [10][1000][108] f32 -> [10][1024][128] bf16, zero-padded ----
__global__ __launch_bounds__(256) void wprep(const float* __restrict__ w,
                                             unsigned short* __restrict__ wbf) {
    const int i = blockIdx.x * 256 + threadIdx.x;
    if (i >= ND * NKP * KPAD) return;
    const int kk   = i & (KPAD - 1);
    const int krow = (i >> 7) & (NKP - 1);
    const int di   = i >> 17;
    float v = 0.f;
    if (krow < KPD && kk < CIN * KL)
        v = w[((size_t)di * KPD + krow) * (CIN * KL) + kk];
    wbf[i] = f2bf(v);
}

// ---- im2col v2: lane = t (coalesced x reads), LDS transpose, linear writeout.
// Strip layout (PRE-SWIZZLED, must match mr_gemm's ds_read):
//   ushort addr = row*KPAD + ((cw*8) ^ ((row&7)<<3)) for 8-tap chunk cw.
__global__ __launch_bounds__(256) void im2col(const float* __restrict__ x,
                                              unsigned short* __restrict__ Aim,
                                              int g0) {
    const int s  = blockIdx.x;
    const int b  = blockIdx.y;
    const int dl = blockIdx.z;
    const int d  = 1 << (g0 + dl);
    const int tid  = threadIdx.x;
    const int lane = tid & 63;
    const int wv   = tid >> 6;

    __shared__ __align__(16) unsigned short sb[STRIP_US];

    const float* xb = x + (size_t)b * CIN * SEQ;
    const int t0 = s * BM;
    const int t  = t0 + lane;            // this lane's output row
    const int base = t - 4 * d;          // SAME padding: pad_lo = 4d
    const bool rowvalid = (t < SEQ);

    // wave wv covers tap-chunks cw = wv*4 .. wv*4+3; for each tap, the 64
    // lanes read consecutive x addresses (coalesced 256B wave-load).
#pragma unroll
    for (int cwi = 0; cwi < 4; ++cwi) {
        const int cw = wv * 4 + cwi;
        u16x8 pk;
        int cc = cw * 8;
        int c = cc / 9, j = cc - c * 9;
#pragma unroll
        for (int e = 0; e < 8; ++e) {
            const int idx = base + j * d;
            float v = 0.f;
            if (rowvalid && cc < CIN * KL && idx >= 0 && idx < SEQ)
                v = xb[c * SEQ + idx];
            pk[e] = f2bf(v);
            ++cc; if (++j == KL) { j = 0; ++c; }
        }
        *(u16x8*)(sb + lane * KPAD + ((cw * 8) ^ ((lane & 7) << 3))) = pk;
    }
    __syncthreads();

    // linear coalesced writeout: 256 threads x 16B x 4 iters = 16KB
    unsigned short* outp = Aim + ((size_t)(dl * NB + b) * SPB + s) * STRIP_US;
#pragma unroll
    for (int i = 0; i < 4; ++i) {
        const int u = (i * 256 + tid) * 8;
        *(u16x8*)(outp + u) = *(const u16x8*)(sb + u);
    }
}

// ---- main GEMM-reduce: block = (dl, ksub of 128 kernels, batch, quarter) ----
__global__ __launch_bounds__(256, 4) void mr_gemm(
    const unsigned short* __restrict__ Aim,
    const unsigned short* __restrict__ wbf,
    const float* __restrict__ bias,
    unsigned* __restrict__ gkey, unsigned* __restrict__ gcnt, int g0)
{
    __shared__ __align__(16) unsigned short lA[2][STRIP_US];  // 32KB dbuf

    // XCD-bijective remap: the 8 ksub-siblings of one (dl,b,q) share phys%8
    // -> same XCD L2 caches their common A-slice once.
    const int phys = blockIdx.x;
    const int gg   = ((phys >> 6) << 3) | (phys & 7);
    const int ksub = (phys >> 3) & 7;
    const int q  = gg & 3;
    const int b  = (gg >> 2) & 15;
    const int dl = gg >> 6;
    const int di = g0 + dl;

    const int tid  = threadIdx.x;
    const int lane = tid & 63;
    const int wv   = tid >> 6;
    const int fr   = lane & 15;
    const int ks   = lane >> 4;

    const int sBeg = q * QS;
    const int sEnd = (q == 3) ? SPB : (sBeg + QS);

    const unsigned short* Ab = Aim + (size_t)(dl * NB + b) * SPB * STRIP_US;
    const unsigned short* wd = wbf + (size_t)di * NKP * KPAD;
    const int kc0 = ksub * 128 + wv * 32 + fr;
    const int kc1 = kc0 + 16;
    const unsigned short* wp = wd + (size_t)kc0 * KPAD + ks * 8;

    // B fragments: loaded ONCE per block (loop-invariant, 32 VGPRs)
    bf16x8 b0[4], b1[4];
#pragma unroll
    for (int kk = 0; kk < 4; ++kk) {
        b0[kk] = *(const bf16x8*)(wp + kk * 32);
        b1[kk] = *(const bf16x8*)(wp + 16 * KPAD + kk * 32);
    }
    const float* bb = bias + (size_t)di * KPD;
    const float bv0 = (kc0 < KPD) ? bb[kc0] : 3.0e38f;
    const float bv1 = (kc1 < KPD) ? bb[kc1] : 3.0e38f;

    float rmax0 = -3.0e38f, rmax1 = -3.0e38f;
    unsigned rcnt0 = 0, rcnt1 = 0;

    // swizzled A-frag base byte addrs (bit7 clear -> +128 folds as imm)
    int abase[4];
#pragma unroll
    for (int m = 0; m < 4; ++m) {
        const int row = m * 16 + fr;
        abase[m] = row * 256 + ((ks * 16) ^ ((row & 7) << 4));
    }

    // prologue: stage strip sBeg into buf0 (linear dest, lane*16 implicit)
    {
        const char* src = (const char*)(Ab + (size_t)sBeg * STRIP_US) + wv * 4096 + lane * 16;
        char* dst = (char*)&lA[0][0] + wv * 4096;
#pragma unroll
        for (int i = 0; i < 4; ++i)
            __builtin_amdgcn_global_load_lds(
                (const __attribute__((address_space(1))) unsigned int*)(src + i * 1024),
                (__attribute__((address_space(3))) unsigned int*)(dst + i * 1024),
                16, 0, 0);
    }
    __syncthreads();

    for (int s = sBeg; s < sEnd; ++s) {
        const int cur = (s - sBeg) & 1;
        if (s + 1 < sEnd) {   // stage next strip into other buffer
            const char* src = (const char*)(Ab + (size_t)(s + 1) * STRIP_US) + wv * 4096 + lane * 16;
            char* dst = (char*)&lA[cur ^ 1][0] + wv * 4096;
#pragma unroll
            for (int i = 0; i < 4; ++i)
                __builtin_amdgcn_global_load_lds(
                    (const __attribute__((address_space(1))) unsigned int*)(src + i * 1024),
                    (__attribute__((address_space(3))) unsigned int*)(dst + i * 1024),
                    16, 0, 0);
        }

        const char* bufc = (const char*)&lA[cur][0];
        f32x4 acc0[4], acc1[4];
#pragma unroll
        for (int m = 0; m < 4; ++m) {
            acc0[m] = (f32x4){0.f, 0.f, 0.f, 0.f};
            acc1[m] = (f32x4){0.f, 0.f, 0.f, 0.f};
        }
        // each A-frag read once, feeds TWO MFMAs (0.5 ds_read/MFMA)
#pragma unroll
        for (int m = 0; m < 4; ++m) {
            const char* pa0 = bufc + abase[m];
            const char* pa1 = bufc + (abase[m] ^ 64);
#pragma unroll
            for (int kk = 0; kk < 4; ++kk) {
                const char* p = (kk & 1) ? pa1 : pa0;
                const bf16x8 a = *(const bf16x8*)(p + (kk >> 1) * 128);
                acc0[m] = __builtin_amdgcn_mfma_f32_16x16x32_bf16(a, b0[kk], acc0[m], 0, 0, 0);
                acc1[m] = __builtin_amdgcn_mfma_f32_16x16x32_bf16(a, b1[kk], acc1[m], 0, 0, 0);
            }
        }

        // per-lane running stats: NO shuffles / atomics per strip
        if (s != SPB - 1) {
            float m0 = -3.0e38f, m1 = -3.0e38f;
            unsigned c0 = 0, c1 = 0;
#pragma unroll
            for (int m = 0; m < 4; ++m) {
#pragma unroll
                for (int r = 0; r < 4; ++r) {
                    const float x0 = acc0[m][r], x1 = acc1[m][r];
                    m0 = fmaxf(m0, x0); c0 += (x0 > bv0) ? 1u : 0u;
                    m1 = fmaxf(m1, x1); c1 += (x1 > bv1) ? 1u : 0u;
                }
            }
            rmax0 = fmaxf(rmax0, m0); rcnt0 += c0;
            rmax1 = fmaxf(rmax1, m1); rcnt1 += c1;
        } else {
            // tail strip 78: rows 4992..5055, valid t<5000 -> rows 0..7 only
            if (ks < 2) {
#pragma unroll
                for (int r = 0; r < 4; ++r) {
                    const float x0 = acc0[0][r], x1 = acc1[0][r];
                    rmax0 = fmaxf(rmax0, x0); rcnt0 += (x0 > bv0) ? 1u : 0u;
                    rmax1 = fmaxf(rmax1, x1); rcnt1 += (x1 > bv1) ? 1u : 0u;
                }
            }
        }
        __syncthreads();   // reads of cur done + stage of cur^1 landed
    }

    // ONE cross-lane reduce + atomic per block (amortized over ~20 strips)
    rmax0 = fmaxf(rmax0, __shfl_xor(rmax0, 16, 64));
    rcnt0 += (unsigned)__shfl_xor((int)rcnt0, 16, 64);
    rmax0 = fmaxf(rmax0, __shfl_xor(rmax0, 32, 64));
    rcnt0 += (unsigned)__shfl_xor((int)rcnt0, 32, 64);
    rmax1 = fmaxf(rmax1, __shfl_xor(rmax1, 16, 64));
    rcnt1 += (unsigned)__shfl_xor((int)rcnt1, 16, 64);
    rmax1 = fmaxf(rmax1, __shfl_xor(rmax1, 32, 64));
    rcnt1 += (unsigned)__shfl_xor((int)rcnt1, 32, 64);

    if (lane < 16) {
        const size_t slotbase = ((size_t)b * ND + di) * KPD;
        if (kc0 < KPD) {
            atomicMax(&gkey[slotbase + kc0], fkey(rmax0));
            atomicAdd(&gcnt[slotbase + kc0], rcnt0);
        }
        if (kc1 < KPD) {
            atomicMax(&gkey[slotbase + kc1], fkey(rmax1));
            atomicAdd(&gcnt[slotbase + kc1], rcnt1);
        }
    }
}

__global__ __launch_bounds__(256) void mr_fin(
    const unsigned* __restrict__ gkey, const unsigned* __restrict__ gcnt,
    float* __restrict__ out)
{
    const int i = blockIdx.x * 256 + threadIdx.x;   // over NB*ND*KPD
    if (i >= NB * ND * KPD) return;
    const int k  = i % KPD;
    const int di = (i / KPD) % ND;
    const int b  = i / (KPD * ND);
    const float maxv = unfkey(gkey[i]);
    const float ppv  = (float)gcnt[i] * (1.0f / (float)SEQ);
    float* ob = out + (size_t)b * (2 * ND * KPD);
    ob[di * 2 * KPD + k]       = maxv;
    ob[di * 2 * KPD + KPD + k] = ppv;
}

extern "C" void kernel_launch(void* const* d_in, const int* in_sizes, int n_in,
                              void* d_out, int out_size, void* d_ws, size_t ws_size,
                              hipStream_t stream) {
    const float* x    = (const float*)d_in[0];
    const float* w    = (const float*)d_in[1];
    const float* bias = (const float*)d_in[2];
    float* out = (float*)d_out;

    const size_t statsB = (size_t)NB * ND * KPD * 4;        // 640,000 B
    const size_t wbfB   = (size_t)ND * NKP * KPAD * 2;      // 2,621,440 B
    unsigned* gkey = (unsigned*)d_ws;
    unsigned* gcnt = (unsigned*)((char*)d_ws + statsB);
    unsigned short* wbf = (unsigned short*)((char*)d_ws + 2 * statsB);
    unsigned short* Aim = (unsigned short*)((char*)d_ws + 2 * statsB + wbfB);

    // group dilations to fit Aim in the available workspace
    const size_t perDil = (size_t)NB * SPB * STRIP_US * 2;  // 20,709,376 B
    const size_t head = 2 * statsB + wbfB;
    size_t avail = (ws_size > head) ? (ws_size - head) : 0;
    int NG = (int)(avail / perDil);
    if (NG > ND) NG = ND;
    if (NG < 1) NG = 1;

    hipMemsetAsync(d_ws, 0, 2 * statsB, stream);

    const int wtot = ND * NKP * KPAD;
    wprep<<<(wtot + 255) / 256, 256, 0, stream>>>(w, wbf);

    for (int g0 = 0; g0 < ND; g0 += NG) {
        const int ng = (ND - g0 < NG) ? (ND - g0) : NG;
        im2col<<<dim3(SPB, NB, ng), 256, 0, stream>>>(x, Aim, g0);
        mr_gemm<<<ng * 512, 256, 0, stream>>>(Aim, wbf, bias, gkey, gcnt, g0);
    }

    const int tot = NB * ND * KPD;
    mr_fin<<<(tot + 255) / 256, 256, 0, stream>>>(gkey, gcnt, out);
}